// Round 2
// baseline (220.861 us; speedup 1.0000x reference)
//
#include <hip/hip_runtime.h>

// Integrator (scaling & squaring) for vel [16,2,512,512] f32, with logdet-Jacobian.
// Intermediate disp stored INTERLEAVED [N,H,W,2] (float2/pixel) to halve gather count;
// final step de-interleaves to planar [N,2,H,W] in d_out.
// Ping-pong: init -> ws ; steps alternate d_out(raw scratch) <-> ws ; step 7 writes planar d_out.
// ws requirement: (8388608 + 4194304) * 4 = 48 MiB.

#define NB 16
#define HH 512
#define WW 512
#define HW (HH * WW)          // 262144 = 1<<18
#define TOT (NB * HW)         // 4194304
#define EPS 0.0078125f        // 2^-7
#define DISP_ELEMS (NB * 2 * HW)   // 8388608 floats = 32 MiB

struct Samp {
    int i00, i01, i10, i11;   // clamped plane offsets (y*W+x)
    float w00, w01, w10, w11; // bilinear weights with OOB folded to 0
};

__device__ __forceinline__ Samp make_samp(float sy, float sx) {
    float fy = floorf(sy), fx = floorf(sx);
    float wy = sy - fy, wx = sx - fx;
    int y0 = (int)fy, x0 = (int)fx;
    int y1 = y0 + 1, x1 = x0 + 1;
    bool xv0 = (unsigned)x0 < (unsigned)WW;
    bool xv1 = (unsigned)x1 < (unsigned)WW;
    bool yv0 = (unsigned)y0 < (unsigned)HH;
    bool yv1 = (unsigned)y1 < (unsigned)HH;
    int xc0 = min(max(x0, 0), WW - 1), xc1 = min(max(x1, 0), WW - 1);
    int yc0 = min(max(y0, 0), HH - 1), yc1 = min(max(y1, 0), HH - 1);
    Samp s;
    s.i00 = yc0 * WW + xc0; s.i01 = yc0 * WW + xc1;
    s.i10 = yc1 * WW + xc0; s.i11 = yc1 * WW + xc1;
    float omwx = 1.0f - wx, omwy = 1.0f - wy;
    s.w00 = (xv0 && yv0) ? omwx * omwy : 0.0f;
    s.w01 = (xv1 && yv0) ? wx * omwy   : 0.0f;
    s.w10 = (xv0 && yv1) ? omwx * wy   : 0.0f;
    s.w11 = (xv1 && yv1) ? wx * wy     : 0.0f;
    return s;
}

__device__ __forceinline__ float logdet4(float a, float b, float c, float d) {
    float tr1 = a + d;
    // X2 = J*J
    float xa = a * a + b * c, xb = a * b + b * d;
    float xc = c * a + d * c, xd = c * b + d * d;
    float tr2 = xa + xd;
    // X3 = X2*J
    float ya = xa * a + xb * c, yb = xa * b + xb * d;
    float yc = xc * a + xd * c, yd = xc * b + xd * d;
    float tr3 = ya + yd;
    // tr(X4) = tr(X3*J)
    float tr4 = ya * a + yb * c + yc * b + yd * d;
    return EPS * tr1 - 0.5f * (EPS * EPS) * tr2
         + (1.0f / 3.0f) * (EPS * EPS * EPS) * tr3
         - 0.25f * (EPS * EPS * EPS * EPS) * tr4;
}

// init: disp0 = eps*vel (interleaved), ldjac0 = logdet series of sobel jacobian.
// 2 horizontally-adjacent pixels per thread; shared 3x4 neighborhood.
__global__ void __launch_bounds__(256) init_kernel(const float* __restrict__ vel,
                                                   float2* __restrict__ ddst,
                                                   float* __restrict__ ldst) {
    int tid = blockIdx.x * 256 + threadIdx.x;
    int pix = tid * 2;
    if (pix >= TOT) return;
    int n = pix >> 18;
    int rem = pix & (HW - 1);
    int y = rem >> 9, x = rem & (WW - 1);   // x is even

    const float* v0 = vel + (size_t)n * 2 * HW;  // vel_y
    const float* v1 = v0 + HW;                   // vel_x

    int r0 = max(y - 1, 0) * WW;
    int r1 = y * WW;
    int r2 = min(y + 1, HH - 1) * WW;
    int c0 = max(x - 1, 0), c1 = x, c2 = x + 1, c3 = min(x + 2, WW - 1);

    float A[3][4], B[3][4];
    int rows[3] = {r0, r1, r2};
    int cols[4] = {c0, c1, c2, c3};
#pragma unroll
    for (int r = 0; r < 3; ++r)
#pragma unroll
        for (int c = 0; c < 4; ++c) {
            A[r][c] = v0[rows[r] + cols[c]];
            B[r][c] = v1[rows[r] + cols[c]];
        }

    // sobel: dy=[[-1,-2,-1],[0,0,0],[1,2,1]], dx=[[-1,0,1],[-2,0,2],[-1,0,1]], x0.125
    float a0 = 0.125f * ((A[2][0] + 2.0f * A[2][1] + A[2][2]) - (A[0][0] + 2.0f * A[0][1] + A[0][2]));
    float b0 = 0.125f * ((A[0][2] + 2.0f * A[1][2] + A[2][2]) - (A[0][0] + 2.0f * A[1][0] + A[2][0]));
    float c0j = 0.125f * ((B[2][0] + 2.0f * B[2][1] + B[2][2]) - (B[0][0] + 2.0f * B[0][1] + B[0][2]));
    float d0j = 0.125f * ((B[0][2] + 2.0f * B[1][2] + B[2][2]) - (B[0][0] + 2.0f * B[1][0] + B[2][0]));

    float a1 = 0.125f * ((A[2][1] + 2.0f * A[2][2] + A[2][3]) - (A[0][1] + 2.0f * A[0][2] + A[0][3]));
    float b1 = 0.125f * ((A[0][3] + 2.0f * A[1][3] + A[2][3]) - (A[0][1] + 2.0f * A[1][1] + A[2][1]));
    float c1j = 0.125f * ((B[2][1] + 2.0f * B[2][2] + B[2][3]) - (B[0][1] + 2.0f * B[0][2] + B[0][3]));
    float d1j = 0.125f * ((B[0][3] + 2.0f * B[1][3] + B[2][3]) - (B[0][1] + 2.0f * B[1][1] + B[2][1]));

    float4 dd;
    dd.x = EPS * A[1][1];  dd.y = EPS * B[1][1];   // px0 (dy, dx)
    dd.z = EPS * A[1][2];  dd.w = EPS * B[1][2];   // px1
    *(float4*)(ddst + (size_t)n * HW + rem) = dd;

    float2 ld;
    ld.x = logdet4(a0, b0, c0j, d0j);
    ld.y = logdet4(a1, b1, c1j, d1j);
    *(float2*)(ldst + (size_t)n * HW + rem) = ld;
}

// one composition step, fused disp + ldjac update, 2 px/thread:
//   disp_new(p)  = disp(p)  + bilerp(disp,  p + disp(p))
//   ldjac_new(p) = ldjac(p) + bilerp(ldjac, p + disp_new(p))
template <bool FINAL>
__global__ void __launch_bounds__(256) step_kernel(const float2* __restrict__ dsrc,
                                                   const float* __restrict__ lsrc,
                                                   float2* __restrict__ ddst2,   // interleaved (!FINAL)
                                                   float* __restrict__ ddstp,    // planar (FINAL)
                                                   float* __restrict__ ldst) {
    int tid = blockIdx.x * 256 + threadIdx.x;
    int pix = tid * 2;
    if (pix >= TOT) return;
    int n = pix >> 18;
    int rem = pix & (HW - 1);
    int y = rem >> 9, x = rem & (WW - 1);   // x even

    const float SC = 512.0f / 511.0f;

    const float2* dp = dsrc + (size_t)n * HW;
    float4 dd = *(const float4*)(dp + rem);   // (dy0,dx0, dy1,dx1)

    // pixel 0
    float nd0a, nd1a;
    {
        float sy = ((float)y + dd.x) * SC - 0.5f;
        float sx = ((float)x + dd.y) * SC - 0.5f;
        Samp s = make_samp(sy, sx);
        float2 g00 = dp[s.i00], g01 = dp[s.i01], g10 = dp[s.i10], g11 = dp[s.i11];
        nd0a = dd.x + s.w00 * g00.x + s.w01 * g01.x + s.w10 * g10.x + s.w11 * g11.x;
        nd1a = dd.y + s.w00 * g00.y + s.w01 * g01.y + s.w10 * g10.y + s.w11 * g11.y;
    }
    // pixel 1
    float nd0b, nd1b;
    {
        float sy = ((float)y + dd.z) * SC - 0.5f;
        float sx = ((float)(x + 1) + dd.w) * SC - 0.5f;
        Samp s = make_samp(sy, sx);
        float2 g00 = dp[s.i00], g01 = dp[s.i01], g10 = dp[s.i10], g11 = dp[s.i11];
        nd0b = dd.z + s.w00 * g00.x + s.w01 * g01.x + s.w10 * g10.x + s.w11 * g11.x;
        nd1b = dd.w + s.w00 * g00.y + s.w01 * g01.y + s.w10 * g10.y + s.w11 * g11.y;
    }

    if (FINAL) {
        float* pdy = ddstp + (size_t)n * 2 * HW;
        float2 wy2; wy2.x = nd0a; wy2.y = nd0b;
        float2 wx2; wx2.x = nd1a; wx2.y = nd1b;
        *(float2*)(pdy + rem) = wy2;
        *(float2*)(pdy + HW + rem) = wx2;
    } else {
        float4 w4; w4.x = nd0a; w4.y = nd1a; w4.z = nd0b; w4.w = nd1b;
        *(float4*)(ddst2 + (size_t)n * HW + rem) = w4;
    }

    // ldjac sampled with the NEW disp at each pixel
    const float* lp = lsrc + (size_t)n * HW;
    float2 l = *(const float2*)(lp + rem);
    float2 nl;
    {
        float sy = ((float)y + nd0a) * SC - 0.5f;
        float sx = ((float)x + nd1a) * SC - 0.5f;
        Samp s = make_samp(sy, sx);
        nl.x = l.x + s.w00 * lp[s.i00] + s.w01 * lp[s.i01]
                   + s.w10 * lp[s.i10] + s.w11 * lp[s.i11];
    }
    {
        float sy = ((float)y + nd0b) * SC - 0.5f;
        float sx = ((float)(x + 1) + nd1b) * SC - 0.5f;
        Samp s = make_samp(sy, sx);
        nl.y = l.y + s.w00 * lp[s.i00] + s.w01 * lp[s.i01]
                   + s.w10 * lp[s.i10] + s.w11 * lp[s.i11];
    }
    *(float2*)(ldst + (size_t)n * HW + rem) = nl;
}

extern "C" void kernel_launch(void* const* d_in, const int* in_sizes, int n_in,
                              void* d_out, int out_size, void* d_ws, size_t ws_size,
                              hipStream_t stream) {
    const float* vel = (const float*)d_in[0];
    float* out = (float*)d_out;
    float* ws = (float*)d_ws;

    // Buffer A = d_out used as raw interleaved scratch until the final step.
    float2* dispA = (float2*)out;
    float*  ldjA  = out + DISP_ELEMS;
    float2* dispB = (float2*)ws;
    float*  ldjB  = ws + DISP_ELEMS;

    dim3 grid(TOT / 2 / 256), block(256);

    // init -> B ; s0:B->A, s1:A->B, s2:B->A, s3:A->B, s4:B->A, s5:A->B, s6:B->planar d_out
    init_kernel<<<grid, block, 0, stream>>>(vel, dispB, ldjB);

    const float2* ds = dispB;
    const float*  ls = ldjB;
    for (int s = 0; s < 6; ++s) {
        float2* dd  = (s & 1) ? dispB : dispA;
        float*  ldd = (s & 1) ? ldjB  : ldjA;
        step_kernel<false><<<grid, block, 0, stream>>>(ds, ls, dd, nullptr, ldd);
        ds = dd; ls = ldd;
    }
    // final step: reads B, writes planar into d_out
    step_kernel<true><<<grid, block, 0, stream>>>(ds, ls, nullptr, out, out + DISP_ELEMS);
}